// Round 7
// baseline (326.181 us; speedup 1.0000x reference)
//
#include <hip/hip_runtime.h>

#define EMBED 1024
#define SEQ   2048
#define BATCH 4
#define HEADS 16

typedef __attribute__((ext_vector_type(8))) short short8;   // 8 bf16 in 4 VGPRs
typedef __attribute__((ext_vector_type(4))) float floatx4;

#define MFMA16(a, b, c) __builtin_amdgcn_mfma_f32_16x16x32_bf16((a), (b), (c), 0, 0, 0)
#define ATT_SCALE (0.125f * 1.44269504088896340736f)   // 1/sqrt(64) * log2(e), folded into Q

static __device__ __forceinline__ unsigned short f2bf(float f) {
  union { float f; unsigned int u; } v; v.f = f;
  unsigned int u = v.u;
  u += 0x7fffu + ((u >> 16) & 1u);       // RNE
  return (unsigned short)(u >> 16);
}

static __device__ __forceinline__ void async16(const unsigned short* g, unsigned short* l) {
  __builtin_amdgcn_global_load_lds(
      (const __attribute__((address_space(1))) void*)g,
      (__attribute__((address_space(3))) void*)l, 16, 0, 0);
}

// ---------------- fp32 -> bf16 elementwise (hidden) ----------------
__global__ __launch_bounds__(256) void k_cvt(const float* __restrict__ src,
                                             unsigned short* __restrict__ dst, int n8) {
  int i = blockIdx.x * 256 + threadIdx.x;
  if (i >= n8) return;
  const float4* s = (const float4*)src;
  float4 a = s[i * 2], b = s[i * 2 + 1];
  uint4 o;
  o.x = (unsigned)f2bf(a.x) | ((unsigned)f2bf(a.y) << 16);
  o.y = (unsigned)f2bf(a.z) | ((unsigned)f2bf(a.w) << 16);
  o.z = (unsigned)f2bf(b.x) | ((unsigned)f2bf(b.y) << 16);
  o.w = (unsigned)f2bf(b.z) | ((unsigned)f2bf(b.w) << 16);
  ((uint4*)dst)[i] = o;
}

// ---------------- W[k][n] -> WT[n][k] bf16 (Wq,Wk,Wv,Wp) ----------------
__global__ __launch_bounds__(256) void k_wt(const float* __restrict__ Wq, const float* __restrict__ Wk,
                                            const float* __restrict__ Wv, const float* __restrict__ Wp,
                                            unsigned short* __restrict__ WT) {
  int z = blockIdx.z;
  const float* src = (z == 0) ? Wq : (z == 1) ? Wk : (z == 2) ? Wv : Wp;
  unsigned short* dst = WT + (size_t)z * EMBED * EMBED;
  int k0 = blockIdx.x * 64, n0 = blockIdx.y * 64;
  __shared__ unsigned short tile[64][65];
  int tid = threadIdx.x;
  for (int i = tid; i < 4096; i += 256) {
    int r = i >> 6, c = i & 63;
    tile[c][r] = f2bf(src[(size_t)(k0 + r) * EMBED + n0 + c]);
  }
  __syncthreads();
  for (int i = tid; i < 4096; i += 256) {
    int r = i >> 6, c = i & 63;
    dst[(size_t)(n0 + r) * EMBED + k0 + c] = tile[r][c];
  }
}

// ---------------- QKV GEMM: C[m][n] = A[m][k]*BT[n][k] + bias, bf16 out -------
// Q columns (n0<1024) pre-scaled by ATT_SCALE so attention needs no mul.
__global__ __launch_bounds__(256) void k_gemm_qkv(const unsigned short* __restrict__ A,
                                                  const unsigned short* __restrict__ BT,
                                                  const float* __restrict__ bq,
                                                  const float* __restrict__ bk,
                                                  const float* __restrict__ bv,
                                                  unsigned short* __restrict__ C) {
  __shared__ unsigned short Als[128 * 64];
  __shared__ unsigned short Bls[128 * 64];
  const int tid = threadIdx.x;
  const int m0 = blockIdx.x * 128, n0 = blockIdx.y * 128;
  const int w = tid >> 6, lane = tid & 63, l16 = lane & 15, quad = lane >> 4;
  const int l7 = l16 & 7;
  const int wrow = (w >> 1) * 64, wcol = (w & 1) * 64;

  floatx4 acc[4][4];
#pragma unroll
  for (int i = 0; i < 4; ++i)
#pragma unroll
    for (int j = 0; j < 4; ++j) acc[i][j] = {0.f, 0.f, 0.f, 0.f};

  const int srow = tid >> 3;
  const int scol = (((tid & 7) ^ (srow & 7)) * 8);
  const unsigned short* Ap = A + (size_t)(m0 + srow) * EMBED + scol;
  const unsigned short* Bp = BT + (size_t)(n0 + srow) * EMBED + scol;

  int ab[2], bb[2];
#pragma unroll
  for (int kc = 0; kc < 2; ++kc) {
    ab[kc] = (wrow + l16) * 64 + (((4 * kc + quad) ^ l7) << 3);
    bb[kc] = (wcol + l16) * 64 + (((4 * kc + quad) ^ l7) << 3);
  }

  for (int kt = 0; kt < 16; ++kt) {
    const int k0 = kt * 64;
#pragma unroll
    for (int i = 0; i < 4; ++i)
      async16(Ap + k0 + (size_t)i * 32 * EMBED, Als + i * 2048 + tid * 8);
#pragma unroll
    for (int i = 0; i < 4; ++i)
      async16(Bp + k0 + (size_t)i * 32 * EMBED, Bls + i * 2048 + tid * 8);
    __syncthreads();
    short8 af[4][2], bf[4][2];
#pragma unroll
    for (int mt = 0; mt < 4; ++mt)
#pragma unroll
      for (int kc = 0; kc < 2; ++kc)
        af[mt][kc] = *(const short8*)(Als + ab[kc] + mt * 1024);
#pragma unroll
    for (int nt = 0; nt < 4; ++nt)
#pragma unroll
      for (int kc = 0; kc < 2; ++kc)
        bf[nt][kc] = *(const short8*)(Bls + bb[kc] + nt * 1024);
#pragma unroll
    for (int kc = 0; kc < 2; ++kc)
#pragma unroll
      for (int mt = 0; mt < 4; ++mt)
#pragma unroll
        for (int nt = 0; nt < 4; ++nt)
          acc[mt][nt] = MFMA16(af[mt][kc], bf[nt][kc], acc[mt][nt]);
    __syncthreads();
  }

  const float* bsel = (n0 < 1024) ? bq : (n0 < 2048 ? bk : bv);
  const float scl = (n0 < 1024) ? ATT_SCALE : 1.0f;
  const int nb = n0 & 1023;
  float bias[4];
#pragma unroll
  for (int nt = 0; nt < 4; ++nt) bias[nt] = bsel[nb + wcol + nt * 16 + l16];
#pragma unroll
  for (int mt = 0; mt < 4; ++mt)
#pragma unroll
    for (int r = 0; r < 4; ++r) {
      int gm = m0 + wrow + mt * 16 + quad * 4 + r;
      size_t base = (size_t)gm * 3072 + n0 + wcol;
#pragma unroll
      for (int nt = 0; nt < 4; ++nt)
        C[base + nt * 16 + l16] = f2bf((acc[mt][nt][r] + bias[nt]) * scl);
    }
}

// ---------------- V[l][d] per (b,h) -> VT[b][h][d][l] ----------------
__global__ __launch_bounds__(256) void k_vt(const unsigned short* __restrict__ QKV,
                                            unsigned short* __restrict__ VT) {
  int lt = blockIdx.x;
  int bh = blockIdx.y;
  int b = bh >> 4, h = bh & 15;
  int l0 = lt * 64;
  __shared__ unsigned short tile[64][65];
  const unsigned short* src = QKV + (size_t)(b * SEQ) * 3072 + 2048 + h * 64;
  unsigned short* dst = VT + (size_t)bh * 64 * SEQ;
  int tid = threadIdx.x;
  for (int i = tid; i < 4096; i += 256) {
    int r = i >> 6, c = i & 63;
    tile[c][r] = src[(size_t)(l0 + r) * 3072 + c];
  }
  __syncthreads();
  for (int i = tid; i < 4096; i += 256) {
    int r = i >> 6, c = i & 63;
    dst[(size_t)r * SEQ + l0 + c] = tile[r][c];
  }
}

// ---------------- attention v7: q-tile 128 for 3 blocks/CU TLP ---------------
// R6 structure (measured 106us) with halved q-tile: wave owns 32 q-rows (mt=2),
// grid(64,16) = 1024 blocks, LDS 8+8+16 = 32 KB, __launch_bounds__(256,3) ->
// 3 blocks/CU = 3 waves/SIMD (was grid-capped at 2). Live VGPR ~140 < 170 cap.
__global__ __launch_bounds__(256, 3) void k_attn(const unsigned short* __restrict__ QKV,
                                                 const unsigned short* __restrict__ VT,
                                                 unsigned short* __restrict__ CTX) {
  const int bh = blockIdx.x, qt = blockIdx.y;
  const int b = bh >> 4, h = bh & 15;
  const int tid = threadIdx.x;
  const int w = tid >> 6, lane = tid & 63, l16 = lane & 15, quad = lane >> 4;

  __shared__ unsigned short Kls[64 * 64];       // [kv][d]  swizzled
  __shared__ unsigned short Vls[64 * 64];       // [d][kv]  swizzled
  __shared__ unsigned short Pls[4][32 * 64];    // per-wave P [32 q][64 kv]  swizzled

  const unsigned short* Qb = QKV + (size_t)(b * SEQ + qt * 128 + w * 32) * 3072 + h * 64;
  const unsigned short* Kb = QKV + (size_t)(b * SEQ) * 3072 + 1024 + h * 64;
  const unsigned short* Vb = VT + (size_t)bh * 64 * SEQ;
  unsigned short* Pw = Pls[w];

  // Q fragments: wave owns 32 q-rows (Q pre-scaled by ATT_SCALE)
  short8 qf[2][2];
#pragma unroll
  for (int mt = 0; mt < 2; ++mt)
#pragma unroll
    for (int kc = 0; kc < 2; ++kc)
      qf[mt][kc] = *(const short8*)(Qb + (size_t)(mt * 16 + l16) * 3072 + kc * 32 + quad * 8);

  floatx4 o[2][4];
  float rs[2][4];
#pragma unroll
  for (int mt = 0; mt < 2; ++mt)
#pragma unroll
    for (int nt = 0; nt < 4; ++nt) o[mt][nt] = {0.f, 0.f, 0.f, 0.f};
#pragma unroll
  for (int mt = 0; mt < 2; ++mt)
#pragma unroll
    for (int r = 0; r < 4; ++r) rs[mt][r] = 0.f;

  const int srow = tid >> 3;                              // 0..31
  const int scol = (((tid & 7) ^ (srow & 7)) * 8);        // swizzled source chunk

  for (int kt = 0; kt < 32; ++kt) {
    const int kv0 = kt * 64;
    async16(Kb + (size_t)(kv0 + srow) * 3072 + scol, Kls + tid * 8);
    async16(Kb + (size_t)(kv0 + 32 + srow) * 3072 + scol, Kls + 2048 + tid * 8);
    async16(Vb + (size_t)srow * SEQ + kv0 + scol, Vls + tid * 8);
    async16(Vb + (size_t)(32 + srow) * SEQ + kv0 + scol, Vls + 2048 + tid * 8);
    __syncthreads();

    // S = Q K^T
    short8 kf[4][2];
#pragma unroll
    for (int nt = 0; nt < 4; ++nt)
#pragma unroll
      for (int kc = 0; kc < 2; ++kc) {
        int row = nt * 16 + l16;
        kf[nt][kc] = *(const short8*)(Kls + row * 64 + (((kc * 4 + quad) ^ (row & 7)) * 8));
      }

#pragma unroll
    for (int mt = 0; mt < 2; ++mt) {
      floatx4 s[4];
#pragma unroll
      for (int nt = 0; nt < 4; ++nt) {
        floatx4 z = {0.f, 0.f, 0.f, 0.f};
        z = MFMA16(qf[mt][0], kf[nt][0], z);
        s[nt] = MFMA16(qf[mt][1], kf[nt][1], z);
      }
      // p = exp2(s); accumulate fp32 row-sums; truncate-to-bf16 into P
#pragma unroll
      for (int nt = 0; nt < 4; ++nt)
#pragma unroll
        for (int r = 0; r < 4; ++r) {
          float p = __builtin_amdgcn_exp2f(s[nt][r]);
          rs[mt][r] += p;
          int row = mt * 16 + quad * 4 + r;
          int col = nt * 16 + l16;
          union { float f; unsigned u; } cv; cv.f = p;
          Pw[row * 64 + (((col >> 3) ^ (row & 7)) * 8) + (col & 7)] = (unsigned short)(cv.u >> 16);
        }
    }

    // per-wave P: LDS pipe is in-order per wave; fence + stop reordering
    __asm__ volatile("s_waitcnt lgkmcnt(0)" ::: "memory");

    // O += P V
    short8 vf[4][2];
#pragma unroll
    for (int nt = 0; nt < 4; ++nt)
#pragma unroll
      for (int kc = 0; kc < 2; ++kc) {
        int row = nt * 16 + l16;
        vf[nt][kc] = *(const short8*)(Vls + row * 64 + (((kc * 4 + quad) ^ (row & 7)) * 8));
      }
#pragma unroll
    for (int kc = 0; kc < 2; ++kc)
#pragma unroll
      for (int mt = 0; mt < 2; ++mt) {
        int row = mt * 16 + l16;
        short8 pf = *(const short8*)(Pw + row * 64 + (((kc * 4 + quad) ^ (row & 7)) * 8));
#pragma unroll
        for (int nt = 0; nt < 4; ++nt)
          o[mt][nt] = MFMA16(pf, vf[nt][kc], o[mt][nt]);
      }
    __syncthreads();   // protect K/V LDS before next staging
  }

  // reduce row-sums across the 16 lanes holding each row's columns
#pragma unroll
  for (int mt = 0; mt < 2; ++mt)
#pragma unroll
    for (int r = 0; r < 4; ++r) {
      float v = rs[mt][r];
#pragma unroll
      for (int off = 1; off < 16; off <<= 1) v += __shfl_xor(v, off);
      rs[mt][r] = 1.f / v;
    }

  // write ctx[b*SEQ + q][h*64 + d] bf16
#pragma unroll
  for (int mt = 0; mt < 2; ++mt)
#pragma unroll
    for (int r = 0; r < 4; ++r) {
      int gq = b * SEQ + qt * 128 + w * 32 + mt * 16 + quad * 4 + r;
      float inv = rs[mt][r];
      size_t base = (size_t)gq * EMBED + h * 64;
#pragma unroll
      for (int nt = 0; nt < 4; ++nt)
        CTX[base + nt * 16 + l16] = f2bf(o[mt][nt][r] * inv);
    }
}

// ---------------- proj GEMM + bias + residual -> fp32 x ----------------
__global__ __launch_bounds__(256) void k_gemm_proj(const unsigned short* __restrict__ A,
                                                   const unsigned short* __restrict__ BT,
                                                   const float* __restrict__ bp,
                                                   const float* __restrict__ hid,
                                                   float* __restrict__ X) {
  __shared__ unsigned short Als[128 * 64];
  __shared__ unsigned short Bls[128 * 64];
  const int tid = threadIdx.x;
  const int m0 = blockIdx.x * 128, n0 = blockIdx.y * 128;
  const int w = tid >> 6, lane = tid & 63, l16 = lane & 15, quad = lane >> 4;
  const int l7 = l16 & 7;
  const int wrow = (w >> 1) * 64, wcol = (w & 1) * 64;

  floatx4 acc[4][4];
#pragma unroll
  for (int i = 0; i < 4; ++i)
#pragma unroll
    for (int j = 0; j < 4; ++j) acc[i][j] = {0.f, 0.f, 0.f, 0.f};

  const int srow = tid >> 3;
  const int scol = (((tid & 7) ^ (srow & 7)) * 8);
  const unsigned short* Ap = A + (size_t)(m0 + srow) * EMBED + scol;
  const unsigned short* Bp = BT + (size_t)(n0 + srow) * EMBED + scol;

  int ab[2], bb[2];
#pragma unroll
  for (int kc = 0; kc < 2; ++kc) {
    ab[kc] = (wrow + l16) * 64 + (((4 * kc + quad) ^ l7) << 3);
    bb[kc] = (wcol + l16) * 64 + (((4 * kc + quad) ^ l7) << 3);
  }

  for (int kt = 0; kt < 16; ++kt) {
    const int k0 = kt * 64;
#pragma unroll
    for (int i = 0; i < 4; ++i)
      async16(Ap + k0 + (size_t)i * 32 * EMBED, Als + i * 2048 + tid * 8);
#pragma unroll
    for (int i = 0; i < 4; ++i)
      async16(Bp + k0 + (size_t)i * 32 * EMBED, Bls + i * 2048 + tid * 8);
    __syncthreads();
    short8 af[4][2], bf[4][2];
#pragma unroll
    for (int mt = 0; mt < 4; ++mt)
#pragma unroll
      for (int kc = 0; kc < 2; ++kc)
        af[mt][kc] = *(const short8*)(Als + ab[kc] + mt * 1024);
#pragma unroll
    for (int nt = 0; nt < 4; ++nt)
#pragma unroll
      for (int kc = 0; kc < 2; ++kc)
        bf[nt][kc] = *(const short8*)(Bls + bb[kc] + nt * 1024);
#pragma unroll
    for (int kc = 0; kc < 2; ++kc)
#pragma unroll
      for (int mt = 0; mt < 4; ++mt)
#pragma unroll
        for (int nt = 0; nt < 4; ++nt)
          acc[mt][nt] = MFMA16(af[mt][kc], bf[nt][kc], acc[mt][nt]);
    __syncthreads();
  }

  float bias[4];
#pragma unroll
  for (int nt = 0; nt < 4; ++nt) bias[nt] = bp[n0 + wcol + nt * 16 + l16];
#pragma unroll
  for (int mt = 0; mt < 4; ++mt)
#pragma unroll
    for (int r = 0; r < 4; ++r) {
      int gm = m0 + wrow + mt * 16 + quad * 4 + r;
      size_t base = (size_t)gm * EMBED + n0 + wcol;
#pragma unroll
      for (int nt = 0; nt < 4; ++nt) {
        size_t idx = base + nt * 16 + l16;
        X[idx] = acc[mt][nt][r] + bias[nt] + hid[idx];
      }
    }
}

// ---------------- in-place LayerNorm over E=1024, one block per row ----------------
__global__ __launch_bounds__(256) void k_ln(float* __restrict__ x,
                                            const float* __restrict__ gamma,
                                            const float* __restrict__ beta) {
  int row = blockIdx.x, tid = threadIdx.x;
  float4* rp = (float4*)(x + (size_t)row * EMBED);
  float4 v = rp[tid];
  float s = v.x + v.y + v.z + v.w;
  float q = v.x * v.x + v.y * v.y + v.z * v.z + v.w * v.w;
#pragma unroll
  for (int off = 1; off < 64; off <<= 1) {
    s += __shfl_xor(s, off);
    q += __shfl_xor(q, off);
  }
  __shared__ float ss[4], sq[4];
  int w = tid >> 6;
  if ((tid & 63) == 0) { ss[w] = s; sq[w] = q; }
  __syncthreads();
  s = ss[0] + ss[1] + ss[2] + ss[3];
  q = sq[0] + sq[1] + sq[2] + sq[3];
  float mean = s * (1.f / 1024.f);
  float var = q * (1.f / 1024.f) - mean * mean;
  float rstd = rsqrtf(var + 1e-8f);
  float4 g = ((const float4*)gamma)[tid];
  float4 be = ((const float4*)beta)[tid];
  v.x = (v.x - mean) * rstd * g.x + be.x;
  v.y = (v.y - mean) * rstd * g.y + be.y;
  v.z = (v.z - mean) * rstd * g.z + be.z;
  v.w = (v.w - mean) * rstd * g.w + be.w;
  rp[tid] = v;
}

extern "C" void kernel_launch(void* const* d_in, const int* in_sizes, int n_in,
                              void* d_out, int out_size, void* d_ws, size_t ws_size,
                              hipStream_t stream) {
  const float* hid   = (const float*)d_in[0];
  const float* Wq    = (const float*)d_in[1];
  const float* bq    = (const float*)d_in[2];
  const float* Wk    = (const float*)d_in[3];
  const float* bk    = (const float*)d_in[4];
  const float* Wv    = (const float*)d_in[5];
  const float* bv    = (const float*)d_in[6];
  const float* Wp    = (const float*)d_in[7];
  const float* bp    = (const float*)d_in[8];
  const float* gamma = (const float*)d_in[9];
  const float* beta  = (const float*)d_in[10];
  float* out = (float*)d_out;

  char* ws = (char*)d_ws;
  unsigned short* hidA = (unsigned short*)ws;                          // 16 MB  [8192][1024]
  unsigned short* WT   = (unsigned short*)(ws + (size_t)(16 << 20));   //  8 MB  [4096][1024]
  unsigned short* QKV  = (unsigned short*)(ws + (size_t)(24 << 20));   // 48 MB  [8192][3072]
  unsigned short* VT   = (unsigned short*)(ws + (size_t)(72 << 20));   // 16 MB  [64][64][2048]
  unsigned short* CTX  = (unsigned short*)(ws + (size_t)(88 << 20));   // 16 MB  [8192][1024]

  k_cvt<<<4096, 256, 0, stream>>>(hid, hidA, (BATCH * SEQ * EMBED) / 8);
  k_wt<<<dim3(16, 16, 4), 256, 0, stream>>>(Wq, Wk, Wv, Wp, WT);
  k_gemm_qkv<<<dim3(64, 24), 256, 0, stream>>>(hidA, WT, bq, bk, bv, QKV);
  k_vt<<<dim3(32, 64), 256, 0, stream>>>(QKV, VT);
  k_attn<<<dim3(64, 16), 256, 0, stream>>>(QKV, VT, CTX);
  k_gemm_proj<<<dim3(64, 8), 256, 0, stream>>>(CTX, WT + (size_t)3 * EMBED * EMBED, bp, hid, out);
  k_ln<<<8192, 256, 0, stream>>>(out, gamma, beta);
}

// Round 8
// 286.729 us; speedup vs baseline: 1.1376x; 1.1376x over previous
//
#include <hip/hip_runtime.h>

#define EMBED 1024
#define SEQ   2048
#define BATCH 4
#define HEADS 16

typedef __attribute__((ext_vector_type(8))) short short8;   // 8 bf16 in 4 VGPRs
typedef __attribute__((ext_vector_type(4))) float floatx4;

#define MFMA16(a, b, c) __builtin_amdgcn_mfma_f32_16x16x32_bf16((a), (b), (c), 0, 0, 0)
#define ATT_SCALE (0.125f * 1.44269504088896340736f)   // 1/sqrt(64) * log2(e), folded into Q

static __device__ __forceinline__ unsigned short f2bf(float f) {
  union { float f; unsigned int u; } v; v.f = f;
  unsigned int u = v.u;
  u += 0x7fffu + ((u >> 16) & 1u);       // RNE
  return (unsigned short)(u >> 16);
}

static __device__ __forceinline__ void async16(const unsigned short* g, unsigned short* l) {
  __builtin_amdgcn_global_load_lds(
      (const __attribute__((address_space(1))) void*)g,
      (__attribute__((address_space(3))) void*)l, 16, 0, 0);
}

// ---------------- fused prep: hidden fp32->bf16 (blocks 0..4095) +
//                  W[k][n]->WT[n][k] bf16 for Wq,Wk,Wv,Wp (blocks 4096..5119) ---
__global__ __launch_bounds__(256) void k_prep(const float* __restrict__ hid,
                                              unsigned short* __restrict__ hidA,
                                              const float* __restrict__ Wq, const float* __restrict__ Wk,
                                              const float* __restrict__ Wv, const float* __restrict__ Wp,
                                              unsigned short* __restrict__ WT) {
  __shared__ unsigned short tile[64][65];
  const int bid = blockIdx.x, tid = threadIdx.x;
  if (bid < 4096) {                       // cvt: 8 floats / thread
    int i = bid * 256 + tid;
    const float4* s = (const float4*)hid;
    float4 a = s[i * 2], b = s[i * 2 + 1];
    uint4 o;
    o.x = (unsigned)f2bf(a.x) | ((unsigned)f2bf(a.y) << 16);
    o.y = (unsigned)f2bf(a.z) | ((unsigned)f2bf(a.w) << 16);
    o.z = (unsigned)f2bf(b.x) | ((unsigned)f2bf(b.y) << 16);
    o.w = (unsigned)f2bf(b.z) | ((unsigned)f2bf(b.w) << 16);
    ((uint4*)hidA)[i] = o;
    return;
  }
  const int idx = bid - 4096;
  const int z = idx >> 8, rem = idx & 255;
  const float* src = (z == 0) ? Wq : (z == 1) ? Wk : (z == 2) ? Wv : Wp;
  unsigned short* dst = WT + (size_t)z * EMBED * EMBED;
  const int k0 = (rem & 15) * 64, n0 = (rem >> 4) * 64;
  for (int i = tid; i < 4096; i += 256) {
    int r = i >> 6, c = i & 63;
    tile[c][r] = f2bf(src[(size_t)(k0 + r) * EMBED + n0 + c]);
  }
  __syncthreads();
  for (int i = tid; i < 4096; i += 256) {
    int r = i >> 6, c = i & 63;
    dst[(size_t)(n0 + r) * EMBED + k0 + c] = tile[r][c];
  }
}

// ---------------- QKV GEMM: C[m][n] = A[m][k]*BT[n][k] + bias, bf16 out -------
// Q columns (n0<1024) pre-scaled by ATT_SCALE so attention needs no mul.
__global__ __launch_bounds__(256) void k_gemm_qkv(const unsigned short* __restrict__ A,
                                                  const unsigned short* __restrict__ BT,
                                                  const float* __restrict__ bq,
                                                  const float* __restrict__ bk,
                                                  const float* __restrict__ bv,
                                                  unsigned short* __restrict__ C) {
  __shared__ unsigned short Als[128 * 64];
  __shared__ unsigned short Bls[128 * 64];
  const int tid = threadIdx.x;
  const int m0 = blockIdx.x * 128, n0 = blockIdx.y * 128;
  const int w = tid >> 6, lane = tid & 63, l16 = lane & 15, quad = lane >> 4;
  const int l7 = l16 & 7;
  const int wrow = (w >> 1) * 64, wcol = (w & 1) * 64;

  floatx4 acc[4][4];
#pragma unroll
  for (int i = 0; i < 4; ++i)
#pragma unroll
    for (int j = 0; j < 4; ++j) acc[i][j] = {0.f, 0.f, 0.f, 0.f};

  const int srow = tid >> 3;
  const int scol = (((tid & 7) ^ (srow & 7)) * 8);
  const unsigned short* Ap = A + (size_t)(m0 + srow) * EMBED + scol;
  const unsigned short* Bp = BT + (size_t)(n0 + srow) * EMBED + scol;

  int ab[2], bb[2];
#pragma unroll
  for (int kc = 0; kc < 2; ++kc) {
    ab[kc] = (wrow + l16) * 64 + (((4 * kc + quad) ^ l7) << 3);
    bb[kc] = (wcol + l16) * 64 + (((4 * kc + quad) ^ l7) << 3);
  }

  for (int kt = 0; kt < 16; ++kt) {
    const int k0 = kt * 64;
#pragma unroll
    for (int i = 0; i < 4; ++i)
      async16(Ap + k0 + (size_t)i * 32 * EMBED, Als + i * 2048 + tid * 8);
#pragma unroll
    for (int i = 0; i < 4; ++i)
      async16(Bp + k0 + (size_t)i * 32 * EMBED, Bls + i * 2048 + tid * 8);
    __syncthreads();
    short8 af[4][2], bf[4][2];
#pragma unroll
    for (int mt = 0; mt < 4; ++mt)
#pragma unroll
      for (int kc = 0; kc < 2; ++kc)
        af[mt][kc] = *(const short8*)(Als + ab[kc] + mt * 1024);
#pragma unroll
    for (int nt = 0; nt < 4; ++nt)
#pragma unroll
      for (int kc = 0; kc < 2; ++kc)
        bf[nt][kc] = *(const short8*)(Bls + bb[kc] + nt * 1024);
#pragma unroll
    for (int kc = 0; kc < 2; ++kc)
#pragma unroll
      for (int mt = 0; mt < 4; ++mt)
#pragma unroll
        for (int nt = 0; nt < 4; ++nt)
          acc[mt][nt] = MFMA16(af[mt][kc], bf[nt][kc], acc[mt][nt]);
    __syncthreads();
  }

  const float* bsel = (n0 < 1024) ? bq : (n0 < 2048 ? bk : bv);
  const float scl = (n0 < 1024) ? ATT_SCALE : 1.0f;
  const int nb = n0 & 1023;
  float bias[4];
#pragma unroll
  for (int nt = 0; nt < 4; ++nt) bias[nt] = bsel[nb + wcol + nt * 16 + l16];
#pragma unroll
  for (int mt = 0; mt < 4; ++mt)
#pragma unroll
    for (int r = 0; r < 4; ++r) {
      int gm = m0 + wrow + mt * 16 + quad * 4 + r;
      size_t base = (size_t)gm * 3072 + n0 + wcol;
#pragma unroll
      for (int nt = 0; nt < 4; ++nt)
        C[base + nt * 16 + l16] = f2bf((acc[mt][nt][r] + bias[nt]) * scl);
    }
}

// ---------------- V[l][d] per (b,h) -> VT[b][h][d][l'] -------------------------
// l' is pi-permuted within each 64-block: position k' holds kv = (k'&3)*16+(k'>>2)
// i.e. k'(kv) = (kv&15)*4 + (kv>>4).  This makes attention's P write contiguous
// (one b64 per (mt,r)) while PV's V-frag stays a natural b128 read.
__global__ __launch_bounds__(256) void k_vt(const unsigned short* __restrict__ QKV,
                                            unsigned short* __restrict__ VT) {
  int lt = blockIdx.x;
  int bh = blockIdx.y;
  int b = bh >> 4, h = bh & 15;
  int l0 = lt * 64;
  __shared__ unsigned short tile[64][65];
  const unsigned short* src = QKV + (size_t)(b * SEQ) * 3072 + 2048 + h * 64;
  unsigned short* dst = VT + (size_t)bh * 64 * SEQ;
  int tid = threadIdx.x;
  for (int i = tid; i < 4096; i += 256) {
    int r = i >> 6, c = i & 63;
    tile[c][r] = src[(size_t)(l0 + r) * 3072 + c];
  }
  __syncthreads();
  for (int i = tid; i < 4096; i += 256) {
    int r = i >> 6, c = i & 63;                       // r: d, c: kv (natural)
    int cp = (c & 15) * 4 + (c >> 4);                 // pi-permuted position
    dst[(size_t)r * SEQ + l0 + cp] = tile[r][c];
  }
}

// ---------------- attention v8 = R6 (106us) + packed P writes -----------------
// P stored in k'-order (k' = l16*4 + nt) so each (mt,r) is ONE ds_write_b64
// (2 v_perm packs) instead of 4 ds_write_b16: P LDS instr/wave/kt 64 -> 16.
// V arrives pi-permuted from k_vt so PV's A (P) and B (V) k-orders match.
// Row-rotate chunk swizzle (chunk' = (chunk + row) & 7) keeps reads 2-way.
__global__ __launch_bounds__(256, 2) void k_attn(const unsigned short* __restrict__ QKV,
                                                 const unsigned short* __restrict__ VT,
                                                 unsigned short* __restrict__ CTX) {
  const int bh = blockIdx.x, qt = blockIdx.y;
  const int b = bh >> 4, h = bh & 15;
  const int tid = threadIdx.x;
  const int w = tid >> 6, lane = tid & 63, l16 = lane & 15, quad = lane >> 4;

  __shared__ unsigned short Kls[64 * 64];       // [kv][d]  xor-chunk swizzled
  __shared__ unsigned short Vls[64 * 64];       // [d][k']  xor-chunk swizzled
  __shared__ unsigned short Pls[4][64 * 64];    // per-wave P [q][k']  rotate-swizzled

  const unsigned short* Qb = QKV + (size_t)(b * SEQ + qt * 256 + w * 64) * 3072 + h * 64;
  const unsigned short* Kb = QKV + (size_t)(b * SEQ) * 3072 + 1024 + h * 64;
  const unsigned short* Vb = VT + (size_t)bh * 64 * SEQ;
  unsigned short* Pw = Pls[w];

  // P write bases (short units): row = mt*16 + quad*4 + r, chunk c8 = l16>>1,
  // chunk' = (c8 + row) & 7, half = l16&1; addr = pwb[r] + mt*1024.
  int pwb[4];
#pragma unroll
  for (int r = 0; r < 4; ++r)
    pwb[r] = (quad * 4 + r) * 64 + ((((l16 >> 1) + quad * 4 + r) & 7) << 3) + ((l16 & 1) << 2);
  // P read bases: row = mt*16 + l16, chunk c8 = kc*4 + quad, chunk' = (c8 + row) & 7.
  int prb[2];
#pragma unroll
  for (int kc = 0; kc < 2; ++kc)
    prb[kc] = l16 * 64 + (((kc * 4 + quad + l16) & 7) << 3);

  // Q fragments: wave owns 64 q-rows (Q pre-scaled by ATT_SCALE)
  short8 qf[4][2];
#pragma unroll
  for (int mt = 0; mt < 4; ++mt)
#pragma unroll
    for (int kc = 0; kc < 2; ++kc)
      qf[mt][kc] = *(const short8*)(Qb + (size_t)(mt * 16 + l16) * 3072 + kc * 32 + quad * 8);

  floatx4 o[4][4];
  float rs[4][4];
#pragma unroll
  for (int mt = 0; mt < 4; ++mt)
#pragma unroll
    for (int nt = 0; nt < 4; ++nt) { o[mt][nt] = {0.f, 0.f, 0.f, 0.f}; rs[mt][nt] = 0.f; }

  const int srow = tid >> 3;                              // 0..31
  const int scol = (((tid & 7) ^ (srow & 7)) * 8);        // swizzled source chunk

  for (int kt = 0; kt < 32; ++kt) {
    const int kv0 = kt * 64;
    async16(Kb + (size_t)(kv0 + srow) * 3072 + scol, Kls + tid * 8);
    async16(Kb + (size_t)(kv0 + 32 + srow) * 3072 + scol, Kls + 2048 + tid * 8);
    async16(Vb + (size_t)srow * SEQ + kv0 + scol, Vls + tid * 8);
    async16(Vb + (size_t)(32 + srow) * SEQ + kv0 + scol, Vls + 2048 + tid * 8);
    __syncthreads();

    // S = Q K^T  (K natural kv order)
    short8 kf[4][2];
#pragma unroll
    for (int nt = 0; nt < 4; ++nt)
#pragma unroll
      for (int kc = 0; kc < 2; ++kc) {
        int row = nt * 16 + l16;
        kf[nt][kc] = *(const short8*)(Kls + row * 64 + (((kc * 4 + quad) ^ (row & 7)) * 8));
      }

#pragma unroll
    for (int mt = 0; mt < 4; ++mt) {
      floatx4 s[4];
#pragma unroll
      for (int nt = 0; nt < 4; ++nt) {
        floatx4 z = {0.f, 0.f, 0.f, 0.f};
        z = MFMA16(qf[mt][0], kf[nt][0], z);
        s[nt] = MFMA16(qf[mt][1], kf[nt][1], z);
      }
      // p = exp2(s); pack 4 nt-values (k' = l16*4+nt contiguous) -> one b64 write
#pragma unroll
      for (int r = 0; r < 4; ++r) {
        union { float f; unsigned u; } c0, c1, c2, c3;
        c0.f = __builtin_amdgcn_exp2f(s[0][r]);
        c1.f = __builtin_amdgcn_exp2f(s[1][r]);
        c2.f = __builtin_amdgcn_exp2f(s[2][r]);
        c3.f = __builtin_amdgcn_exp2f(s[3][r]);
        rs[mt][r] += (c0.f + c1.f) + (c2.f + c3.f);
        uint2 pk;
        pk.x = __builtin_amdgcn_perm(c1.u, c0.u, 0x07060302);  // [bf(p0), bf(p1)]
        pk.y = __builtin_amdgcn_perm(c3.u, c2.u, 0x07060302);  // [bf(p2), bf(p3)]
        *(uint2*)(Pw + pwb[r] + mt * 1024) = pk;
      }
    }

    // per-wave P: LDS pipe is in-order per wave; fence + stop reordering
    __asm__ volatile("s_waitcnt lgkmcnt(0)" ::: "memory");

    // O += P V  (both in k' order)
    short8 vf[4][2];
#pragma unroll
    for (int nt = 0; nt < 4; ++nt)
#pragma unroll
      for (int kc = 0; kc < 2; ++kc) {
        int row = nt * 16 + l16;
        vf[nt][kc] = *(const short8*)(Vls + row * 64 + (((kc * 4 + quad) ^ (row & 7)) * 8));
      }
#pragma unroll
    for (int kc = 0; kc < 2; ++kc)
#pragma unroll
      for (int mt = 0; mt < 4; ++mt) {
        short8 pf = *(const short8*)(Pw + prb[kc] + mt * 1024);
#pragma unroll
        for (int nt = 0; nt < 4; ++nt)
          o[mt][nt] = MFMA16(pf, vf[nt][kc], o[mt][nt]);
      }
    __syncthreads();   // protect K/V LDS before next staging
  }

  // reduce row-sums across the 16 lanes holding each row's columns
#pragma unroll
  for (int mt = 0; mt < 4; ++mt)
#pragma unroll
    for (int r = 0; r < 4; ++r) {
      float v = rs[mt][r];
#pragma unroll
      for (int off = 1; off < 16; off <<= 1) v += __shfl_xor(v, off);
      rs[mt][r] = 1.f / v;
    }

  // write ctx[b*SEQ + q][h*64 + d] bf16
#pragma unroll
  for (int mt = 0; mt < 4; ++mt)
#pragma unroll
    for (int r = 0; r < 4; ++r) {
      int gq = b * SEQ + qt * 256 + w * 64 + mt * 16 + quad * 4 + r;
      float inv = rs[mt][r];
      size_t base = (size_t)gq * EMBED + h * 64;
#pragma unroll
      for (int nt = 0; nt < 4; ++nt)
        CTX[base + nt * 16 + l16] = f2bf(o[mt][nt][r] * inv);
    }
}

// ---------------- proj GEMM + bias + residual -> fp32 x ----------------
__global__ __launch_bounds__(256) void k_gemm_proj(const unsigned short* __restrict__ A,
                                                   const unsigned short* __restrict__ BT,
                                                   const float* __restrict__ bp,
                                                   const float* __restrict__ hid,
                                                   float* __restrict__ X) {
  __shared__ unsigned short Als[128 * 64];
  __shared__ unsigned short Bls[128 * 64];
  const int tid = threadIdx.x;
  const int m0 = blockIdx.x * 128, n0 = blockIdx.y * 128;
  const int w = tid >> 6, lane = tid & 63, l16 = lane & 15, quad = lane >> 4;
  const int l7 = l16 & 7;
  const int wrow = (w >> 1) * 64, wcol = (w & 1) * 64;

  floatx4 acc[4][4];
#pragma unroll
  for (int i = 0; i < 4; ++i)
#pragma unroll
    for (int j = 0; j < 4; ++j) acc[i][j] = {0.f, 0.f, 0.f, 0.f};

  const int srow = tid >> 3;
  const int scol = (((tid & 7) ^ (srow & 7)) * 8);
  const unsigned short* Ap = A + (size_t)(m0 + srow) * EMBED + scol;
  const unsigned short* Bp = BT + (size_t)(n0 + srow) * EMBED + scol;

  int ab[2], bb[2];
#pragma unroll
  for (int kc = 0; kc < 2; ++kc) {
    ab[kc] = (wrow + l16) * 64 + (((4 * kc + quad) ^ l7) << 3);
    bb[kc] = (wcol + l16) * 64 + (((4 * kc + quad) ^ l7) << 3);
  }

  for (int kt = 0; kt < 16; ++kt) {
    const int k0 = kt * 64;
#pragma unroll
    for (int i = 0; i < 4; ++i)
      async16(Ap + k0 + (size_t)i * 32 * EMBED, Als + i * 2048 + tid * 8);
#pragma unroll
    for (int i = 0; i < 4; ++i)
      async16(Bp + k0 + (size_t)i * 32 * EMBED, Bls + i * 2048 + tid * 8);
    __syncthreads();
    short8 af[4][2], bf[4][2];
#pragma unroll
    for (int mt = 0; mt < 4; ++mt)
#pragma unroll
      for (int kc = 0; kc < 2; ++kc)
        af[mt][kc] = *(const short8*)(Als + ab[kc] + mt * 1024);
#pragma unroll
    for (int nt = 0; nt < 4; ++nt)
#pragma unroll
      for (int kc = 0; kc < 2; ++kc)
        bf[nt][kc] = *(const short8*)(Bls + bb[kc] + nt * 1024);
#pragma unroll
    for (int kc = 0; kc < 2; ++kc)
#pragma unroll
      for (int mt = 0; mt < 4; ++mt)
#pragma unroll
        for (int nt = 0; nt < 4; ++nt)
          acc[mt][nt] = MFMA16(af[mt][kc], bf[nt][kc], acc[mt][nt]);
    __syncthreads();
  }

  float bias[4];
#pragma unroll
  for (int nt = 0; nt < 4; ++nt) bias[nt] = bp[n0 + wcol + nt * 16 + l16];
#pragma unroll
  for (int mt = 0; mt < 4; ++mt)
#pragma unroll
    for (int r = 0; r < 4; ++r) {
      int gm = m0 + wrow + mt * 16 + quad * 4 + r;
      size_t base = (size_t)gm * EMBED + n0 + wcol;
#pragma unroll
      for (int nt = 0; nt < 4; ++nt) {
        size_t idx = base + nt * 16 + l16;
        X[idx] = acc[mt][nt][r] + bias[nt] + hid[idx];
      }
    }
}

// ---------------- in-place LayerNorm over E=1024, one block per row ----------------
__global__ __launch_bounds__(256) void k_ln(float* __restrict__ x,
                                            const float* __restrict__ gamma,
                                            const float* __restrict__ beta) {
  int row = blockIdx.x, tid = threadIdx.x;
  float4* rp = (float4*)(x + (size_t)row * EMBED);
  float4 v = rp[tid];
  float s = v.x + v.y + v.z + v.w;
  float q = v.x * v.x + v.y * v.y + v.z * v.z + v.w * v.w;
#pragma unroll
  for (int off = 1; off < 64; off <<= 1) {
    s += __shfl_xor(s, off);
    q += __shfl_xor(q, off);
  }
  __shared__ float ss[4], sq[4];
  int w = tid >> 6;
  if ((tid & 63) == 0) { ss[w] = s; sq[w] = q; }
  __syncthreads();
  s = ss[0] + ss[1] + ss[2] + ss[3];
  q = sq[0] + sq[1] + sq[2] + sq[3];
  float mean = s * (1.f / 1024.f);
  float var = q * (1.f / 1024.f) - mean * mean;
  float rstd = rsqrtf(var + 1e-8f);
  float4 g = ((const float4*)gamma)[tid];
  float4 be = ((const float4*)beta)[tid];
  v.x = (v.x - mean) * rstd * g.x + be.x;
  v.y = (v.y - mean) * rstd * g.y + be.y;
  v.z = (v.z - mean) * rstd * g.z + be.z;
  v.w = (v.w - mean) * rstd * g.w + be.w;
  rp[tid] = v;
}

extern "C" void kernel_launch(void* const* d_in, const int* in_sizes, int n_in,
                              void* d_out, int out_size, void* d_ws, size_t ws_size,
                              hipStream_t stream) {
  const float* hid   = (const float*)d_in[0];
  const float* Wq    = (const float*)d_in[1];
  const float* bq    = (const float*)d_in[2];
  const float* Wk    = (const float*)d_in[3];
  const float* bk    = (const float*)d_in[4];
  const float* Wv    = (const float*)d_in[5];
  const float* bv    = (const float*)d_in[6];
  const float* Wp    = (const float*)d_in[7];
  const float* bp    = (const float*)d_in[8];
  const float* gamma = (const float*)d_in[9];
  const float* beta  = (const float*)d_in[10];
  float* out = (float*)d_out;

  char* ws = (char*)d_ws;
  unsigned short* hidA = (unsigned short*)ws;                          // 16 MB  [8192][1024]
  unsigned short* WT   = (unsigned short*)(ws + (size_t)(16 << 20));   //  8 MB  [4096][1024]
  unsigned short* QKV  = (unsigned short*)(ws + (size_t)(24 << 20));   // 48 MB  [8192][3072]
  unsigned short* VT   = (unsigned short*)(ws + (size_t)(72 << 20));   // 16 MB  [64][64][2048]
  unsigned short* CTX  = (unsigned short*)(ws + (size_t)(88 << 20));   // 16 MB  [8192][1024]

  k_prep<<<5120, 256, 0, stream>>>(hid, hidA, Wq, Wk, Wv, Wp, WT);
  k_gemm_qkv<<<dim3(64, 24), 256, 0, stream>>>(hidA, WT, bq, bk, bv, QKV);
  k_vt<<<dim3(32, 64), 256, 0, stream>>>(QKV, VT);
  k_attn<<<dim3(64, 8), 256, 0, stream>>>(QKV, VT, CTX);
  k_gemm_proj<<<dim3(64, 8), 256, 0, stream>>>(CTX, WT + (size_t)3 * EMBED * EMBED, bp, hid, out);
  k_ln<<<8192, 256, 0, stream>>>(out, gamma, beta);
}